// Round 15
// baseline (317.979 us; speedup 1.0000x reference)
//
#include <hip/hip_runtime.h>
#include <math.h>

constexpr int B_ = 8, N_ = 1024, F_ = 256, H_ = 4, U_ = 256;
constexpr int BH_ = B_ * H_;
constexpr int CH_ = 16;          // scan chunk length
constexpr int NCH_ = N_ / CH_;   // 64 chunks
constexpr int M_ = B_ * N_;      // 8192 GEMM rows per head

typedef short short8 __attribute__((ext_vector_type(8)));
typedef float floatx4 __attribute__((ext_vector_type(4)));

__device__ inline unsigned short f2bf(float f) {
    unsigned u = __float_as_uint(f);
    u += 0x7fff + ((u >> 16) & 1);          // round-to-nearest-even
    return (unsigned short)(u >> 16);
}
__device__ inline float bf2f(unsigned short s) { return __uint_as_float(((unsigned)s) << 16); }

__device__ inline void gload_lds16(const void* g, void* l) {
    __builtin_amdgcn_global_load_lds(
        (const __attribute__((address_space(1))) void*)g,
        (__attribute__((address_space(3))) void*)(unsigned)(uintptr_t)l,
        16, 0, 0);
}

// ---------------- prep_w: blocks 0..63 = W transpose->bf16; 64..79 = c_src/c_dst
__global__ __launch_bounds__(256) void prep_w(const float* __restrict__ W,
                                              const float* __restrict__ asr,
                                              const float* __restrict__ ads,
                                              unsigned short* __restrict__ whT,
                                              float* __restrict__ c_src,
                                              float* __restrict__ c_dst) {
    int tid = threadIdx.x;
    if (blockIdx.x < 64) {
        __shared__ float t[64][65];
        int bi = blockIdx.x;
        int f0 = (bi & 3) * 64, u0 = ((bi >> 2) & 3) * 64, h = bi >> 4;
        int c = tid & 63, rbase = tid >> 6;
        #pragma unroll
        for (int rr = 0; rr < 16; ++rr) {
            int r = rr * 4 + rbase;
            t[r][c] = W[((size_t)(h * F_ + f0 + r)) * U_ + u0 + c];
        }
        __syncthreads();
        #pragma unroll
        for (int rr = 0; rr < 16; ++rr) {
            int r = rr * 4 + rbase;                 // u-local
            whT[((size_t)(h * U_ + u0 + r)) * F_ + f0 + c] = f2bf(t[c][r]);
        }
    } else {
        int id = blockIdx.x - 64;                   // 0..15
        int h = id >> 2, f0 = (id & 3) * 64;
        int fl = tid >> 2, q = tid & 3;
        int f = f0 + fl;
        const float* Wrow = W + ((size_t)(h * F_ + f)) * U_ + q * 64;
        const float* av = asr + h * U_ + q * 64;
        const float* bv = ads + h * U_ + q * 64;
        float s = 0.f, d = 0.f;
        #pragma unroll
        for (int u = 0; u < 64; ++u) { float ww = Wrow[u]; s += ww * av[u]; d += ww * bv[u]; }
        s += __shfl_xor(s, 1); s += __shfl_xor(s, 2);
        d += __shfl_xor(d, 1); d += __shfl_xor(d, 2);
        if (q == 0) { c_src[h * F_ + f] = s; c_dst[h * F_ + f] = d; }
    }
}

// ---------------- K1b: fused x->bf16 + src/dst dots (wave per row) --------------
__global__ __launch_bounds__(256) void k1b_fused(const float* __restrict__ x,
                                                 const float* __restrict__ c_src,
                                                 const float* __restrict__ c_dst,
                                                 unsigned short* __restrict__ xh,
                                                 float* __restrict__ srcv,
                                                 float* __restrict__ dstv) {
    int tid = threadIdx.x;
    int lane = tid & 63, w = tid >> 6;
    int row = blockIdx.x * 4 + w;           // 0..B*N-1
    int b = row >> 10, n = row & 1023;
    const float4 x4 = *(const float4*)(x + (size_t)row * F_ + lane * 4);
    ushort4 hv;
    hv.x = f2bf(x4.x); hv.y = f2bf(x4.y); hv.z = f2bf(x4.z); hv.w = f2bf(x4.w);
    ((ushort4*)xh)[(size_t)row * (F_ / 4) + lane] = hv;
    #pragma unroll
    for (int hh = 0; hh < H_; ++hh) {
        float4 c4 = *(const float4*)(c_src + hh * F_ + lane * 4);
        float s = x4.x*c4.x + x4.y*c4.y + x4.z*c4.z + x4.w*c4.w;
        #pragma unroll
        for (int off = 32; off; off >>= 1) s += __shfl_xor(s, off);
        float4 d4 = *(const float4*)(c_dst + hh * F_ + lane * 4);
        float d = x4.x*d4.x + x4.y*d4.y + x4.z*d4.z + x4.w*d4.w;
        #pragma unroll
        for (int off = 32; off; off >>= 1) d += __shfl_xor(d, off);
        if (lane == 0) {
            srcv[(size_t)(b * H_ + hh) * N_ + n] = s;
            dstv[(size_t)(b * H_ + hh) * N_ + n] = d;
        }
    }
}

// ---------------- K2: two interleaved bitonic sorts + pos search + cstart -------
__global__ __launch_bounds__(1024) void k2_all(const float* __restrict__ dstv,
                                               const float* __restrict__ srcv,
                                               float* __restrict__ dvs,
                                               int* __restrict__ invp,
                                               int* __restrict__ spos,
                                               int* __restrict__ srows,
                                               float* __restrict__ se8,
                                               int* __restrict__ cstart) {
    __shared__ float dv[N_];
    __shared__ float keyLA[N_]; __shared__ int idxLA[N_];
    __shared__ float keyLB[N_]; __shared__ int idxLB[N_];
    int bh = blockIdx.x, t = threadIdx.x;

    float ka = dstv[(size_t)bh * N_ + t];  int ia = t;   // sort A: dst ascending
    float kb = -srcv[(size_t)bh * N_ + t]; int ib = t;   // sort B: src descending

    for (int k = 2; k <= N_; k <<= 1) {
        for (int j = k >> 1; j > 0; j >>= 1) {
            bool up = ((t & k) == 0);
            bool lower = ((t & j) == 0);
            float oa, ob; int oia, oib;
            if (j >= 64) {
                keyLA[t] = ka; idxLA[t] = ia;
                keyLB[t] = kb; idxLB[t] = ib;
                __syncthreads();
                oa = keyLA[t ^ j]; oia = idxLA[t ^ j];
                ob = keyLB[t ^ j]; oib = idxLB[t ^ j];
                __syncthreads();
            } else {
                oa = __shfl_xor(ka, j); oia = __shfl_xor(ia, j);
                ob = __shfl_xor(kb, j); oib = __shfl_xor(ib, j);
            }
            bool swa = up ? (lower ? (ka > oa) : (ka < oa))
                          : (lower ? (ka < oa) : (ka > oa));
            if (swa) { ka = oa; ia = oia; }
            bool swb = up ? (lower ? (kb > ob) : (kb < ob))
                          : (lower ? (kb < ob) : (kb > ob));
            if (swb) { kb = ob; ib = oib; }
        }
    }

    dvs[(size_t)bh * N_ + t] = ka;
    invp[(size_t)bh * N_ + ia] = t;         // sorted slot of original row
    dv[t] = ka;
    __syncthreads();                        // dv[] complete

    float s = -kb;
    int lo = 0, hi = N_;
    while (lo < hi) {                       // pos = count(dv <= -s)
        int mid = (lo + hi) >> 1;
        if (dv[mid] <= kb) lo = mid + 1; else hi = mid;
    }
    spos[(size_t)bh * N_ + t] = lo;
    srows[(size_t)bh * N_ + t] = ib;
    se8[(size_t)bh * N_ + t] = expf(0.8f * s);
    idxLA[t] = lo;                          // reuse as pos[]
    __syncthreads();
    if (t < NCH_ + 1) {                     // cstart[c] = lower_bound(pos, c*CH_)
        int target = t * CH_;
        int lo2 = 0, hi2 = N_;
        while (lo2 < hi2) {
            int mid = (lo2 + hi2) >> 1;
            if (idxLA[mid] < target) lo2 = mid + 1; else hi2 = mid;
        }
        cstart[bh * (NCH_ + 1) + t] = lo2;
    }
}

// ---------------- K1: pure bf16 MFMA; LDS-transposed coalesced bf16 epilogue ----
__global__ __launch_bounds__(256) void k1_mfma(const unsigned short* __restrict__ xh,
                                               const unsigned short* __restrict__ whT,
                                               const int* __restrict__ invp,
                                               unsigned short* __restrict__ hbuf) {
    __shared__ __align__(16) unsigned short As[2 * 128 * 64];   // 32 KB; B = As+8192
    __shared__ int jsL[128];
    unsigned short* Bs = As + 128 * 64;
    const int tid = threadIdx.x;
    const int lane = tid & 63, wv = tid >> 6;
    const int wr = wv >> 1, wc = wv & 1;
    const int m0 = blockIdx.x * 128;
    const int u0 = blockIdx.y * 128;
    const int hh = blockIdx.z;
    const int b = m0 >> 10, n0 = m0 & 1023;
    const int bh = b * H_ + hh;

    // hoisted: invp load overlaps the whole MFMA main loop
    if (tid < 128) jsL[tid] = invp[(size_t)bh * N_ + n0 + tid];

    floatx4 acc[4][4] = {};

    const char* Asrc = (const char*)xh;
    const char* Bsrc = (const char*)(whT + (size_t)hh * U_ * F_);

    const int ch_row = lane >> 3;
    const int ch_col = (lane & 7) * 16;

    for (int t = 0; t < 4; ++t) {
        const size_t kb = (size_t)t * 128;       // 64 bf16 k-slice
        #pragma unroll
        for (int i = 0; i < 4; ++i) {
            int c = wv * 4 + i;
            int row = c * 8 + ch_row;
            gload_lds16(Asrc + (size_t)(m0 + row) * 512 + kb + ch_col,
                        (char*)As + c * 1024);
            gload_lds16(Bsrc + (size_t)(u0 + row) * 512 + kb + ch_col,
                        (char*)Bs + c * 1024);
        }
        __syncthreads();
        #pragma unroll
        for (int ks = 0; ks < 2; ++ks) {
            short8 af[4], bfr[4];
            #pragma unroll
            for (int mf = 0; mf < 4; ++mf) {
                int row = wr * 64 + mf * 16 + (lane & 15);
                af[mf] = *(const short8*)&As[row * 64 + ks * 32 + (lane >> 4) * 8];
            }
            #pragma unroll
            for (int nf = 0; nf < 4; ++nf) {
                int row = wc * 64 + nf * 16 + (lane & 15);
                bfr[nf] = *(const short8*)&Bs[row * 64 + ks * 32 + (lane >> 4) * 8];
            }
            #pragma unroll
            for (int mf = 0; mf < 4; ++mf)
                #pragma unroll
                for (int nf = 0; nf < 4; ++nf)
                    acc[mf][nf] = __builtin_amdgcn_mfma_f32_16x16x32_bf16(
                        af[mf], bfr[nf], acc[mf][nf], 0, 0, 0);
        }
        __syncthreads();
    }

    // epilogue: acc -> LDS (bf16, 128x128) -> coalesced ushort8 scattered-row store
    unsigned short* S = As;                      // reuse full 32 KB
    const int rquad = (lane >> 4) * 4;
    const int ucol = lane & 15;
    #pragma unroll
    for (int mf = 0; mf < 4; ++mf)
        #pragma unroll
        for (int j = 0; j < 4; ++j) {
            int rloc = wr * 64 + mf * 16 + rquad + j;
            #pragma unroll
            for (int nf = 0; nf < 4; ++nf)
                S[rloc * 128 + wc * 64 + nf * 16 + ucol] = f2bf(acc[mf][nf][j]);
        }
    __syncthreads();
    #pragma unroll
    for (int i = 0; i < 8; ++i) {
        int flat = tid + i * 256;                // 0..2047
        int rloc = flat >> 4, slot = flat & 15;
        short8 v = *(const short8*)&S[rloc * 128 + slot * 8];
        *(short8*)&hbuf[((size_t)bh * N_ + jsL[rloc]) * U_ + u0 + slot * 8] = v;
    }
}

// ---------------- K3a: chunk partial sums + last-block-per-bh prefix bases ------
__global__ __launch_bounds__(256) void k3a_partial(const unsigned short* __restrict__ hbuf,
                                                   const float* __restrict__ dvs,
                                                   float* __restrict__ cT1, float* __restrict__ cT2,
                                                   float* __restrict__ cZ1, float* __restrict__ cZ2,
                                                   float* __restrict__ b1, float* __restrict__ b2,
                                                   float* __restrict__ bz1, float* __restrict__ bz2,
                                                   int* __restrict__ cnt) {
    __shared__ float w1s[CH_], w2s[CH_];
    __shared__ floatx4 A1s[4][64], A2s[4][64];
    __shared__ int amLast;
    int bh = blockIdx.x / NCH_, c = blockIdx.x % NCH_;
    int tid = threadIdx.x, w = tid >> 6, l = tid & 63;
    const ushort4* hb4 = (const ushort4*)(hbuf + ((size_t)bh * N_ + c * CH_) * U_);
    ushort4 h0 = hb4[(4 * w + 0) * 64 + l];
    ushort4 h1 = hb4[(4 * w + 1) * 64 + l];
    ushort4 h2 = hb4[(4 * w + 2) * 64 + l];
    ushort4 h3 = hb4[(4 * w + 3) * 64 + l];
    floatx4 v0 = {bf2f(h0.x), bf2f(h0.y), bf2f(h0.z), bf2f(h0.w)};
    floatx4 v1 = {bf2f(h1.x), bf2f(h1.y), bf2f(h1.z), bf2f(h1.w)};
    floatx4 v2 = {bf2f(h2.x), bf2f(h2.y), bf2f(h2.z), bf2f(h2.w)};
    floatx4 v3 = {bf2f(h3.x), bf2f(h3.y), bf2f(h3.z), bf2f(h3.w)};
    if (tid < CH_) {
        float vv = dvs[(size_t)bh * N_ + c * CH_ + tid];
        w1s[tid] = expf(vv);
        w2s[tid] = expf(0.2f * vv);
    }
    __syncthreads();
    floatx4 s1 = w1s[4*w]*v0 + w1s[4*w+1]*v1 + w1s[4*w+2]*v2 + w1s[4*w+3]*v3;
    floatx4 s2 = w2s[4*w]*v0 + w2s[4*w+1]*v1 + w2s[4*w+2]*v2 + w2s[4*w+3]*v3;
    A1s[w][l] = s1; A2s[w][l] = s2;
    __syncthreads();
    if (tid < 64) {
        floatx4 r1 = A1s[0][tid] + A1s[1][tid] + A1s[2][tid] + A1s[3][tid];
        floatx4 r2 = A2s[0][tid] + A2s[1][tid] + A2s[2][tid] + A2s[3][tid];
        ((floatx4*)(cT1 + (size_t)(bh * NCH_ + c) * U_))[tid] = r1;
        ((floatx4*)(cT2 + (size_t)(bh * NCH_ + c) * U_))[tid] = r2;
    }
    if (tid == 0) {
        float z1 = 0.f, z2 = 0.f;
        #pragma unroll
        for (int r = 0; r < CH_; ++r) { z1 += w1s[r]; z2 += w2s[r]; }
        cZ1[bh * NCH_ + c] = z1; cZ2[bh * NCH_ + c] = z2;
    }

    // ---- tail: last finishing block of this bh computes the chunk-prefix bases -
    __threadfence();                              // release cT/cZ writes
    if (tid == 0) amLast = (atomicAdd(&cnt[bh], 1) == NCH_ - 1) ? 1 : 0;
    __syncthreads();
    if (!amLast) return;
    __threadfence();                              // acquire other blocks' writes

    __shared__ float tt1[4][64], tt2[4][64];
    const int seg = w;                            // 4 segments x 16 chunks
    #pragma unroll
    for (int q = 0; q < 4; ++q) {                 // u-quarter (exact k3b FP order)
        int ucol = q * 64 + l;
        float v1r[16], v2r[16];
        #pragma unroll
        for (int k = 0; k < 16; ++k) {
            int cc = seg * 16 + k;
            v1r[k] = cT1[(size_t)(bh * NCH_ + cc) * U_ + ucol];
            v2r[k] = cT2[(size_t)(bh * NCH_ + cc) * U_ + ucol];
        }
        float T1 = 0.f, T2 = 0.f;
        #pragma unroll
        for (int k = 0; k < 16; ++k) { T1 += v1r[k]; T2 += v2r[k]; }
        tt1[seg][l] = T1; tt2[seg][l] = T2;
        __syncthreads();
        float base2 = 0.f, base1 = 0.f;
        #pragma unroll
        for (int ss = 0; ss < 4; ++ss) {
            if (ss < seg) base2 += tt2[ss][l];
            if (ss > seg) base1 += tt1[ss][l];
        }
        float acc2 = base2;
        #pragma unroll
        for (int k = 0; k < 16; ++k) {
            b2[(size_t)(bh * NCH_ + seg * 16 + k) * U_ + ucol] = acc2;
            acc2 += v2r[k];
        }
        float acc1 = base1;
        #pragma unroll
        for (int k = 15; k >= 0; --k) {
            b1[(size_t)(bh * NCH_ + seg * 16 + k) * U_ + ucol] = acc1;
            acc1 += v1r[k];
        }
        __syncthreads();                          // tt reused next q
    }

    if (tid < NCH_) {                             // one wave: Z scalar scans
        int u = tid;
        float z1 = cZ1[bh * NCH_ + u];
        float z2 = cZ2[bh * NCH_ + u];
        float i1 = z1, i2 = z2;
        #pragma unroll
        for (int off = 1; off < NCH_; off <<= 1) {
            float t1 = __shfl_up(i1, off, 64);
            float t2 = __shfl_up(i2, off, 64);
            if (u >= off) { i1 += t1; i2 += t2; }
        }
        float tot = __shfl(i1, NCH_ - 1, 64);
        bz1[bh * NCH_ + u] = tot - i1;            // suffix-exclusive
        bz2[bh * NCH_ + u] = i2 - z2;             // prefix-exclusive
    }
}

// ---------------- K3cd: scan (bf16 in) -> emission; early loads, NT out stores --
__global__ __launch_bounds__(256) void k3cd_emit(const unsigned short* __restrict__ hbuf,
                                                 const float* __restrict__ dvs,
                                                 const float* __restrict__ b1, const float* __restrict__ b2,
                                                 const float* __restrict__ bz1, const float* __restrict__ bz2,
                                                 const int* __restrict__ spos,
                                                 const int* __restrict__ srows,
                                                 const float* __restrict__ se8,
                                                 const int* __restrict__ cstart,
                                                 float* __restrict__ out) {
    __shared__ floatx4 P1s[CH_ + 1][64];   // P1s[r][l] = sum of rows < r (u=4l..4l+3)
    __shared__ floatx4 P2s[CH_ + 1][64];
    __shared__ floatx4 T1s[4][64], T2s[4][64];
    __shared__ float w1s[CH_], w2s[CH_];
    __shared__ float zx1[CH_ + 1], zx2[CH_ + 1];
    __shared__ int sps[256], srs[256];
    __shared__ float s8s[256];

    int bh = blockIdx.x / NCH_, c = blockIdx.x % NCH_;
    int tid = threadIdx.x, w = tid >> 6, l = tid & 63;
    int b = bh >> 2, hh = bh & 3;

    // --- early: issue ALL dependent global loads so they overlap the scan phase -
    const int*   spos_b  = spos  + (size_t)bh * N_;
    const int*   srows_b = srows + (size_t)bh * N_;
    const float* se8_b   = se8   + (size_t)bh * N_;
    const int j0 = cstart[bh * (NCH_ + 1) + c];
    const int e0 = (c == NCH_ - 1) ? N_ : cstart[bh * (NCH_ + 1) + c + 1];
    int sp0 = 0, sr0 = 0; float s80 = 0.f;
    {
        int jj = j0 + tid;
        if (jj < e0) { sp0 = spos_b[jj]; sr0 = srows_b[jj]; s80 = se8_b[jj]; }
    }
    floatx4 b1u = ((const floatx4*)(b1 + (size_t)(bh * NCH_ + c) * U_))[l];
    floatx4 b2u = ((const floatx4*)(b2 + (size_t)(bh * NCH_ + c) * U_))[l];
    float bz1c = bz1[bh * NCH_ + c], bz2c = bz2[bh * NCH_ + c];

    const ushort4* hb4 = (const ushort4*)(hbuf + ((size_t)bh * N_ + c * CH_) * U_);
    ushort4 h0 = hb4[(4 * w + 0) * 64 + l];
    ushort4 h1 = hb4[(4 * w + 1) * 64 + l];
    ushort4 h2 = hb4[(4 * w + 2) * 64 + l];
    ushort4 h3 = hb4[(4 * w + 3) * 64 + l];
    floatx4 v0 = {bf2f(h0.x), bf2f(h0.y), bf2f(h0.z), bf2f(h0.w)};
    floatx4 v1 = {bf2f(h1.x), bf2f(h1.y), bf2f(h1.z), bf2f(h1.w)};
    floatx4 v2 = {bf2f(h2.x), bf2f(h2.y), bf2f(h2.z), bf2f(h2.w)};
    floatx4 v3 = {bf2f(h3.x), bf2f(h3.y), bf2f(h3.z), bf2f(h3.w)};
    if (tid < CH_) {
        float vv = dvs[(size_t)bh * N_ + c * CH_ + tid];
        w1s[tid] = expf(vv);
        w2s[tid] = expf(0.2f * vv);
    }
    __syncthreads();
    float a0 = w1s[4*w], a1 = w1s[4*w+1], a2 = w1s[4*w+2], a3 = w1s[4*w+3];
    float c0 = w2s[4*w], c1 = w2s[4*w+1], c2 = w2s[4*w+2], c3 = w2s[4*w+3];
    floatx4 q1_1 = a0 * v0;
    floatx4 q1_2 = q1_1 + a1 * v1;
    floatx4 q1_3 = q1_2 + a2 * v2;
    floatx4 tw1  = q1_3 + a3 * v3;
    floatx4 q2_1 = c0 * v0;
    floatx4 q2_2 = q2_1 + c1 * v1;
    floatx4 q2_3 = q2_2 + c2 * v2;
    floatx4 tw2  = q2_3 + c3 * v3;
    T1s[w][l] = tw1; T2s[w][l] = tw2;
    if (tid == 0) {
        float z1 = 0.f, z2 = 0.f;
        #pragma unroll
        for (int r = 0; r < CH_; ++r) { zx1[r] = z1; zx2[r] = z2; z1 += w1s[r]; z2 += w2s[r]; }
        zx1[CH_] = z1; zx2[CH_] = z2;
    }
    __syncthreads();
    floatx4 base1 = {0.f, 0.f, 0.f, 0.f}, base2 = {0.f, 0.f, 0.f, 0.f};
    if (w > 0) { base1 += T1s[0][l]; base2 += T2s[0][l]; }
    if (w > 1) { base1 += T1s[1][l]; base2 += T2s[1][l]; }
    if (w > 2) { base1 += T1s[2][l]; base2 += T2s[2][l]; }
    P1s[4*w+0][l] = base1;         P2s[4*w+0][l] = base2;
    P1s[4*w+1][l] = base1 + q1_1;  P2s[4*w+1][l] = base2 + q2_1;
    P1s[4*w+2][l] = base1 + q1_2;  P2s[4*w+2][l] = base2 + q2_2;
    P1s[4*w+3][l] = base1 + q1_3;  P2s[4*w+3][l] = base2 + q2_3;
    if (w == 3) { P1s[CH_][l] = base1 + tw1; P2s[CH_][l] = base2 + tw2; }
    __syncthreads();

    floatx4 t1 = P1s[CH_][l];
    float tz1 = zx1[CH_];

    for (int t0 = j0; t0 < e0; t0 += 256) {
        if (t0 == j0) {
            sps[tid] = sp0; srs[tid] = sr0; s8s[tid] = s80;   // registers, no latency
        } else {
            int jj = t0 + tid;
            if (jj < e0) { sps[tid] = spos_b[jj]; srs[tid] = srows_b[jj]; s8s[tid] = se8_b[jj]; }
        }
        __syncthreads();
        int cnt2 = min(256, e0 - t0);
        for (int k = w; k < cnt2; k += 4) {          // 4 rows in flight (one per wave)
            int   rr  = sps[k] - c * CH_;            // 0..CH_, uniform per wave
            int   row = srs[k];
            float e8  = s8s[k];
            floatx4 s1 = b1u + (t1 - P1s[rr][l]);
            floatx4 s2 = b2u + P2s[rr][l];
            float den = e8 * (bz1c + (tz1 - zx1[rr])) + (bz2c + zx2[rr]);
            float rden = 1.0f / den;
            floatx4 o = (e8 * s1 + s2) * rden;
            __builtin_nontemporal_store(o,
                (floatx4*)(out + ((size_t)(b * N_ + row)) * (H_ * U_) + hh * U_ + 4 * l));
        }
        __syncthreads();
    }
}

// ---------------- host launch ----------------------------------------------------
extern "C" void kernel_launch(void* const* d_in, const int* in_sizes, int n_in,
                              void* d_out, int out_size, void* d_ws, size_t ws_size,
                              hipStream_t stream) {
    const float* x    = (const float*)d_in[0];
    const float* W    = (const float*)d_in[1];
    const float* asr  = (const float*)d_in[2];
    const float* ads  = (const float*)d_in[3];
    float* out = (float*)d_out;

    char* ws = (char*)d_ws;
    size_t off = 0;
    auto alloc = [&](size_t nfloats) -> float* {
        float* p = (float*)(ws + off);
        off += ((nfloats * 4 + 255) / 256) * 256;
        return p;
    };
    unsigned short* hbuf = (unsigned short*)alloc((size_t)BH_ * N_ * U_ / 2);  // 16.7 MB bf16
    float* srcv  = alloc((size_t)BH_ * N_);
    float* dstv  = alloc((size_t)BH_ * N_);
    float* c_src = alloc(H_ * F_);
    float* c_dst = alloc(H_ * F_);
    float* dvs   = alloc((size_t)BH_ * N_);
    int*   invp  = (int*)alloc((size_t)BH_ * N_);
    int*   srows = (int*)alloc((size_t)BH_ * N_);
    int*   spos  = (int*)alloc((size_t)BH_ * N_);
    float* se8   = alloc((size_t)BH_ * N_);
    int*   cstart= (int*)alloc(BH_ * (NCH_ + 1));
    float* cT1   = alloc((size_t)BH_ * NCH_ * U_);        // 2 MB
    float* cT2   = alloc((size_t)BH_ * NCH_ * U_);
    float* cZ1   = alloc(BH_ * NCH_);
    float* cZ2   = alloc(BH_ * NCH_);
    float* b1    = alloc((size_t)BH_ * NCH_ * U_);
    float* b2    = alloc((size_t)BH_ * NCH_ * U_);
    float* bz1   = alloc(BH_ * NCH_);
    float* bz2   = alloc(BH_ * NCH_);
    int*   cnt   = (int*)alloc(BH_);
    unsigned short* xh  = (unsigned short*)alloc((size_t)M_ * F_ / 2);   // 4.2 MB
    unsigned short* whT = (unsigned short*)alloc((size_t)H_ * U_ * F_ / 2);
    (void)ws_size; (void)in_sizes; (void)n_in; (void)out_size;

    hipMemsetAsync(cnt, 0, BH_ * sizeof(int), stream);    // reset completion counters
    prep_w<<<80, 256, 0, stream>>>(W, asr, ads, whT, c_src, c_dst);
    k1b_fused<<<(B_ * N_) / 4, 256, 0, stream>>>(x, c_src, c_dst, xh, srcv, dstv);
    k2_all<<<BH_, 1024, 0, stream>>>(dstv, srcv, dvs, invp, spos, srows, se8, cstart);
    k1_mfma<<<dim3(M_ / 128, U_ / 128, H_), 256, 0, stream>>>(xh, whT, invp, hbuf);
    k3a_partial<<<BH_ * NCH_, 256, 0, stream>>>(hbuf, dvs, cT1, cT2, cZ1, cZ2,
                                                b1, b2, bz1, bz2, cnt);
    k3cd_emit<<<BH_ * NCH_, 256, 0, stream>>>(hbuf, dvs, b1, b2, bz1, bz2,
                                              spos, srows, se8, cstart, out);
}

// Round 16
// 79.661 us; speedup vs baseline: 3.9916x; 3.9916x over previous
//
#include <hip/hip_runtime.h>
#include <math.h>

constexpr int B_ = 8, N_ = 1024, F_ = 256, H_ = 4, U_ = 256;
constexpr int BH_ = B_ * H_;
constexpr int CH_ = 16;          // scan chunk length
constexpr int NCH_ = N_ / CH_;   // 64 chunks
constexpr int M_ = B_ * N_;      // 8192 GEMM rows per head

typedef short short8 __attribute__((ext_vector_type(8)));
typedef float floatx4 __attribute__((ext_vector_type(4)));

__device__ inline unsigned short f2bf(float f) {
    unsigned u = __float_as_uint(f);
    u += 0x7fff + ((u >> 16) & 1);          // round-to-nearest-even
    return (unsigned short)(u >> 16);
}
__device__ inline float bf2f(unsigned short s) { return __uint_as_float(((unsigned)s) << 16); }

__device__ inline void gload_lds16(const void* g, void* l) {
    __builtin_amdgcn_global_load_lds(
        (const __attribute__((address_space(1))) void*)g,
        (__attribute__((address_space(3))) void*)(unsigned)(uintptr_t)l,
        16, 0, 0);
}

// ---------------- prep_w: blocks 0..63 = W transpose->bf16; 64..79 = c_src/c_dst
__global__ __launch_bounds__(256) void prep_w(const float* __restrict__ W,
                                              const float* __restrict__ asr,
                                              const float* __restrict__ ads,
                                              unsigned short* __restrict__ whT,
                                              float* __restrict__ c_src,
                                              float* __restrict__ c_dst) {
    int tid = threadIdx.x;
    if (blockIdx.x < 64) {
        __shared__ float t[64][65];
        int bi = blockIdx.x;
        int f0 = (bi & 3) * 64, u0 = ((bi >> 2) & 3) * 64, h = bi >> 4;
        int c = tid & 63, rbase = tid >> 6;
        #pragma unroll
        for (int rr = 0; rr < 16; ++rr) {
            int r = rr * 4 + rbase;
            t[r][c] = W[((size_t)(h * F_ + f0 + r)) * U_ + u0 + c];
        }
        __syncthreads();
        #pragma unroll
        for (int rr = 0; rr < 16; ++rr) {
            int r = rr * 4 + rbase;                 // u-local
            whT[((size_t)(h * U_ + u0 + r)) * F_ + f0 + c] = f2bf(t[c][r]);
        }
    } else {
        int id = blockIdx.x - 64;                   // 0..15
        int h = id >> 2, f0 = (id & 3) * 64;
        int fl = tid >> 2, q = tid & 3;
        int f = f0 + fl;
        const float* Wrow = W + ((size_t)(h * F_ + f)) * U_ + q * 64;
        const float* av = asr + h * U_ + q * 64;
        const float* bv = ads + h * U_ + q * 64;
        float s = 0.f, d = 0.f;
        #pragma unroll
        for (int u = 0; u < 64; ++u) { float ww = Wrow[u]; s += ww * av[u]; d += ww * bv[u]; }
        s += __shfl_xor(s, 1); s += __shfl_xor(s, 2);
        d += __shfl_xor(d, 1); d += __shfl_xor(d, 2);
        if (q == 0) { c_src[h * F_ + f] = s; c_dst[h * F_ + f] = d; }
    }
}

// ---------------- K1b: fused x->bf16 + src/dst dots (wave per row) --------------
__global__ __launch_bounds__(256) void k1b_fused(const float* __restrict__ x,
                                                 const float* __restrict__ c_src,
                                                 const float* __restrict__ c_dst,
                                                 unsigned short* __restrict__ xh,
                                                 float* __restrict__ srcv,
                                                 float* __restrict__ dstv) {
    int tid = threadIdx.x;
    int lane = tid & 63, w = tid >> 6;
    int row = blockIdx.x * 4 + w;           // 0..B*N-1
    int b = row >> 10, n = row & 1023;
    const float4 x4 = *(const float4*)(x + (size_t)row * F_ + lane * 4);
    ushort4 hv;
    hv.x = f2bf(x4.x); hv.y = f2bf(x4.y); hv.z = f2bf(x4.z); hv.w = f2bf(x4.w);
    ((ushort4*)xh)[(size_t)row * (F_ / 4) + lane] = hv;
    #pragma unroll
    for (int hh = 0; hh < H_; ++hh) {
        float4 c4 = *(const float4*)(c_src + hh * F_ + lane * 4);
        float s = x4.x*c4.x + x4.y*c4.y + x4.z*c4.z + x4.w*c4.w;
        #pragma unroll
        for (int off = 32; off; off >>= 1) s += __shfl_xor(s, off);
        float4 d4 = *(const float4*)(c_dst + hh * F_ + lane * 4);
        float d = x4.x*d4.x + x4.y*d4.y + x4.z*d4.z + x4.w*d4.w;
        #pragma unroll
        for (int off = 32; off; off >>= 1) d += __shfl_xor(d, off);
        if (lane == 0) {
            srcv[(size_t)(b * H_ + hh) * N_ + n] = s;
            dstv[(size_t)(b * H_ + hh) * N_ + n] = d;
        }
    }
}

// ---------------- K2: two interleaved bitonic sorts + pos search + cstart -------
__global__ __launch_bounds__(1024) void k2_all(const float* __restrict__ dstv,
                                               const float* __restrict__ srcv,
                                               float* __restrict__ dvs,
                                               int* __restrict__ invp,
                                               int* __restrict__ spos,
                                               int* __restrict__ srows,
                                               float* __restrict__ se8,
                                               int* __restrict__ cstart) {
    __shared__ float dv[N_];
    __shared__ float keyLA[N_]; __shared__ int idxLA[N_];
    __shared__ float keyLB[N_]; __shared__ int idxLB[N_];
    int bh = blockIdx.x, t = threadIdx.x;

    float ka = dstv[(size_t)bh * N_ + t];  int ia = t;   // sort A: dst ascending
    float kb = -srcv[(size_t)bh * N_ + t]; int ib = t;   // sort B: src descending

    for (int k = 2; k <= N_; k <<= 1) {
        for (int j = k >> 1; j > 0; j >>= 1) {
            bool up = ((t & k) == 0);
            bool lower = ((t & j) == 0);
            float oa, ob; int oia, oib;
            if (j >= 64) {
                keyLA[t] = ka; idxLA[t] = ia;
                keyLB[t] = kb; idxLB[t] = ib;
                __syncthreads();
                oa = keyLA[t ^ j]; oia = idxLA[t ^ j];
                ob = keyLB[t ^ j]; oib = idxLB[t ^ j];
                __syncthreads();
            } else {
                oa = __shfl_xor(ka, j); oia = __shfl_xor(ia, j);
                ob = __shfl_xor(kb, j); oib = __shfl_xor(ib, j);
            }
            bool swa = up ? (lower ? (ka > oa) : (ka < oa))
                          : (lower ? (ka < oa) : (ka > oa));
            if (swa) { ka = oa; ia = oia; }
            bool swb = up ? (lower ? (kb > ob) : (kb < ob))
                          : (lower ? (kb < ob) : (kb > ob));
            if (swb) { kb = ob; ib = oib; }
        }
    }

    dvs[(size_t)bh * N_ + t] = ka;
    invp[(size_t)bh * N_ + ia] = t;         // sorted slot of original row
    dv[t] = ka;
    __syncthreads();                        // dv[] complete

    float s = -kb;
    int lo = 0, hi = N_;
    while (lo < hi) {                       // pos = count(dv <= -s)
        int mid = (lo + hi) >> 1;
        if (dv[mid] <= kb) lo = mid + 1; else hi = mid;
    }
    spos[(size_t)bh * N_ + t] = lo;
    srows[(size_t)bh * N_ + t] = ib;
    se8[(size_t)bh * N_ + t] = expf(0.8f * s);
    idxLA[t] = lo;                          // reuse as pos[]
    __syncthreads();
    if (t < NCH_ + 1) {                     // cstart[c] = lower_bound(pos, c*CH_)
        int target = t * CH_;
        int lo2 = 0, hi2 = N_;
        while (lo2 < hi2) {
            int mid = (lo2 + hi2) >> 1;
            if (idxLA[mid] < target) lo2 = mid + 1; else hi2 = mid;
        }
        cstart[bh * (NCH_ + 1) + t] = lo2;
    }
}

// ---------------- K1: pure bf16 MFMA; LDS-transposed coalesced bf16 epilogue ----
__global__ __launch_bounds__(256) void k1_mfma(const unsigned short* __restrict__ xh,
                                               const unsigned short* __restrict__ whT,
                                               const int* __restrict__ invp,
                                               unsigned short* __restrict__ hbuf) {
    __shared__ __align__(16) unsigned short As[2 * 128 * 64];   // 32 KB; B = As+8192
    __shared__ int jsL[128];
    unsigned short* Bs = As + 128 * 64;
    const int tid = threadIdx.x;
    const int lane = tid & 63, wv = tid >> 6;
    const int wr = wv >> 1, wc = wv & 1;
    const int m0 = blockIdx.x * 128;
    const int u0 = blockIdx.y * 128;
    const int hh = blockIdx.z;
    const int b = m0 >> 10, n0 = m0 & 1023;
    const int bh = b * H_ + hh;

    // hoisted: invp load overlaps the whole MFMA main loop
    if (tid < 128) jsL[tid] = invp[(size_t)bh * N_ + n0 + tid];

    floatx4 acc[4][4] = {};

    const char* Asrc = (const char*)xh;
    const char* Bsrc = (const char*)(whT + (size_t)hh * U_ * F_);

    const int ch_row = lane >> 3;
    const int ch_col = (lane & 7) * 16;

    for (int t = 0; t < 4; ++t) {
        const size_t kb = (size_t)t * 128;       // 64 bf16 k-slice
        #pragma unroll
        for (int i = 0; i < 4; ++i) {
            int c = wv * 4 + i;
            int row = c * 8 + ch_row;
            gload_lds16(Asrc + (size_t)(m0 + row) * 512 + kb + ch_col,
                        (char*)As + c * 1024);
            gload_lds16(Bsrc + (size_t)(u0 + row) * 512 + kb + ch_col,
                        (char*)Bs + c * 1024);
        }
        __syncthreads();
        #pragma unroll
        for (int ks = 0; ks < 2; ++ks) {
            short8 af[4], bfr[4];
            #pragma unroll
            for (int mf = 0; mf < 4; ++mf) {
                int row = wr * 64 + mf * 16 + (lane & 15);
                af[mf] = *(const short8*)&As[row * 64 + ks * 32 + (lane >> 4) * 8];
            }
            #pragma unroll
            for (int nf = 0; nf < 4; ++nf) {
                int row = wc * 64 + nf * 16 + (lane & 15);
                bfr[nf] = *(const short8*)&Bs[row * 64 + ks * 32 + (lane >> 4) * 8];
            }
            #pragma unroll
            for (int mf = 0; mf < 4; ++mf)
                #pragma unroll
                for (int nf = 0; nf < 4; ++nf)
                    acc[mf][nf] = __builtin_amdgcn_mfma_f32_16x16x32_bf16(
                        af[mf], bfr[nf], acc[mf][nf], 0, 0, 0);
        }
        __syncthreads();
    }

    // epilogue: acc -> LDS (bf16, 128x128) -> coalesced ushort8 scattered-row store
    unsigned short* S = As;                      // reuse full 32 KB
    const int rquad = (lane >> 4) * 4;
    const int ucol = lane & 15;
    #pragma unroll
    for (int mf = 0; mf < 4; ++mf)
        #pragma unroll
        for (int j = 0; j < 4; ++j) {
            int rloc = wr * 64 + mf * 16 + rquad + j;
            #pragma unroll
            for (int nf = 0; nf < 4; ++nf)
                S[rloc * 128 + wc * 64 + nf * 16 + ucol] = f2bf(acc[mf][nf][j]);
        }
    __syncthreads();
    #pragma unroll
    for (int i = 0; i < 8; ++i) {
        int flat = tid + i * 256;                // 0..2047
        int rloc = flat >> 4, slot = flat & 15;
        short8 v = *(const short8*)&S[rloc * 128 + slot * 8];
        *(short8*)&hbuf[((size_t)bh * N_ + jsL[rloc]) * U_ + u0 + slot * 8] = v;
    }
}

// ---------------- K3a: per-chunk partial sums — bf16x4 loads, 4 rows/wave -------
__global__ __launch_bounds__(256) void k3a_partial(const unsigned short* __restrict__ hbuf,
                                                   const float* __restrict__ dvs,
                                                   float* __restrict__ cT1, float* __restrict__ cT2,
                                                   float* __restrict__ cZ1, float* __restrict__ cZ2) {
    __shared__ float w1s[CH_], w2s[CH_];
    __shared__ floatx4 A1s[4][64], A2s[4][64];
    int bh = blockIdx.x / NCH_, c = blockIdx.x % NCH_;
    int tid = threadIdx.x, w = tid >> 6, l = tid & 63;
    const ushort4* hb4 = (const ushort4*)(hbuf + ((size_t)bh * N_ + c * CH_) * U_);
    ushort4 h0 = hb4[(4 * w + 0) * 64 + l];
    ushort4 h1 = hb4[(4 * w + 1) * 64 + l];
    ushort4 h2 = hb4[(4 * w + 2) * 64 + l];
    ushort4 h3 = hb4[(4 * w + 3) * 64 + l];
    floatx4 v0 = {bf2f(h0.x), bf2f(h0.y), bf2f(h0.z), bf2f(h0.w)};
    floatx4 v1 = {bf2f(h1.x), bf2f(h1.y), bf2f(h1.z), bf2f(h1.w)};
    floatx4 v2 = {bf2f(h2.x), bf2f(h2.y), bf2f(h2.z), bf2f(h2.w)};
    floatx4 v3 = {bf2f(h3.x), bf2f(h3.y), bf2f(h3.z), bf2f(h3.w)};
    if (tid < CH_) {
        float vv = dvs[(size_t)bh * N_ + c * CH_ + tid];
        w1s[tid] = expf(vv);
        w2s[tid] = expf(0.2f * vv);
    }
    __syncthreads();
    floatx4 s1 = w1s[4*w]*v0 + w1s[4*w+1]*v1 + w1s[4*w+2]*v2 + w1s[4*w+3]*v3;
    floatx4 s2 = w2s[4*w]*v0 + w2s[4*w+1]*v1 + w2s[4*w+2]*v2 + w2s[4*w+3]*v3;
    A1s[w][l] = s1; A2s[w][l] = s2;
    __syncthreads();
    if (tid < 64) {
        floatx4 r1 = A1s[0][tid] + A1s[1][tid] + A1s[2][tid] + A1s[3][tid];
        floatx4 r2 = A2s[0][tid] + A2s[1][tid] + A2s[2][tid] + A2s[3][tid];
        ((floatx4*)(cT1 + (size_t)(bh * NCH_ + c) * U_))[tid] = r1;
        ((floatx4*)(cT2 + (size_t)(bh * NCH_ + c) * U_))[tid] = r2;
    }
    if (tid == 0) {
        float z1 = 0.f, z2 = 0.f;
        #pragma unroll
        for (int r = 0; r < CH_; ++r) { z1 += w1s[r]; z2 += w2s[r]; }
        cZ1[bh * NCH_ + c] = z1; cZ2[bh * NCH_ + c] = z2;
    }
}

// ---------------- K3b: widened segment-scan — 128 blocks, 4 segs x 16 chunks ----
__global__ __launch_bounds__(256) void k3b_combine(const float* __restrict__ cT1, const float* __restrict__ cT2,
                                                   const float* __restrict__ cZ1, const float* __restrict__ cZ2,
                                                   float* __restrict__ b1, float* __restrict__ b2,
                                                   float* __restrict__ bz1, float* __restrict__ bz2) {
    __shared__ float tot1[4][64], tot2[4][64];
    int bh = blockIdx.x >> 2, q = blockIdx.x & 3;
    int l = threadIdx.x & 63, seg = threadIdx.x >> 6;
    int ucol = q * 64 + l;

    float v1[16], v2[16];
    #pragma unroll
    for (int k = 0; k < 16; ++k) {
        int cc = seg * 16 + k;
        v1[k] = cT1[(size_t)(bh * NCH_ + cc) * U_ + ucol];
        v2[k] = cT2[(size_t)(bh * NCH_ + cc) * U_ + ucol];
    }
    float T1 = 0.f, T2 = 0.f;
    #pragma unroll
    for (int k = 0; k < 16; ++k) { T1 += v1[k]; T2 += v2[k]; }
    tot1[seg][l] = T1; tot2[seg][l] = T2;
    __syncthreads();
    float base2 = 0.f, base1 = 0.f;
    #pragma unroll
    for (int ss = 0; ss < 4; ++ss) {
        if (ss < seg) base2 += tot2[ss][l];
        if (ss > seg) base1 += tot1[ss][l];
    }
    float acc2 = base2;
    #pragma unroll
    for (int k = 0; k < 16; ++k) {
        b2[(size_t)(bh * NCH_ + seg * 16 + k) * U_ + ucol] = acc2;
        acc2 += v2[k];
    }
    float acc1 = base1;
    #pragma unroll
    for (int k = 15; k >= 0; --k) {
        b1[(size_t)(bh * NCH_ + seg * 16 + k) * U_ + ucol] = acc1;
        acc1 += v1[k];
    }

    if (q == 0 && threadIdx.x < NCH_) {      // one wave: Z scalar scans
        int u = threadIdx.x;
        float z1 = cZ1[bh * NCH_ + u];
        float z2 = cZ2[bh * NCH_ + u];
        float i1 = z1, i2 = z2;
        #pragma unroll
        for (int off = 1; off < NCH_; off <<= 1) {
            float t1 = __shfl_up(i1, off, 64);
            float t2 = __shfl_up(i2, off, 64);
            if (u >= off) { i1 += t1; i2 += t2; }
        }
        float tot = __shfl(i1, NCH_ - 1, 64);
        bz1[bh * NCH_ + u] = tot - i1;       // suffix-exclusive
        bz2[bh * NCH_ + u] = i2 - z2;        // prefix-exclusive
    }
}

// ---------------- K3cd: scan (bf16 in) -> emission; early loads, NT out stores --
__global__ __launch_bounds__(256) void k3cd_emit(const unsigned short* __restrict__ hbuf,
                                                 const float* __restrict__ dvs,
                                                 const float* __restrict__ b1, const float* __restrict__ b2,
                                                 const float* __restrict__ bz1, const float* __restrict__ bz2,
                                                 const int* __restrict__ spos,
                                                 const int* __restrict__ srows,
                                                 const float* __restrict__ se8,
                                                 const int* __restrict__ cstart,
                                                 float* __restrict__ out) {
    __shared__ floatx4 P1s[CH_ + 1][64];   // P1s[r][l] = sum of rows < r (u=4l..4l+3)
    __shared__ floatx4 P2s[CH_ + 1][64];
    __shared__ floatx4 T1s[4][64], T2s[4][64];
    __shared__ float w1s[CH_], w2s[CH_];
    __shared__ float zx1[CH_ + 1], zx2[CH_ + 1];
    __shared__ int sps[256], srs[256];
    __shared__ float s8s[256];

    int bh = blockIdx.x / NCH_, c = blockIdx.x % NCH_;
    int tid = threadIdx.x, w = tid >> 6, l = tid & 63;
    int b = bh >> 2, hh = bh & 3;

    // --- early: issue ALL dependent global loads so they overlap the scan phase -
    const int*   spos_b  = spos  + (size_t)bh * N_;
    const int*   srows_b = srows + (size_t)bh * N_;
    const float* se8_b   = se8   + (size_t)bh * N_;
    const int j0 = cstart[bh * (NCH_ + 1) + c];
    const int e0 = (c == NCH_ - 1) ? N_ : cstart[bh * (NCH_ + 1) + c + 1];
    int sp0 = 0, sr0 = 0; float s80 = 0.f;
    {
        int jj = j0 + tid;
        if (jj < e0) { sp0 = spos_b[jj]; sr0 = srows_b[jj]; s80 = se8_b[jj]; }
    }
    floatx4 b1u = ((const floatx4*)(b1 + (size_t)(bh * NCH_ + c) * U_))[l];
    floatx4 b2u = ((const floatx4*)(b2 + (size_t)(bh * NCH_ + c) * U_))[l];
    float bz1c = bz1[bh * NCH_ + c], bz2c = bz2[bh * NCH_ + c];

    const ushort4* hb4 = (const ushort4*)(hbuf + ((size_t)bh * N_ + c * CH_) * U_);
    ushort4 h0 = hb4[(4 * w + 0) * 64 + l];
    ushort4 h1 = hb4[(4 * w + 1) * 64 + l];
    ushort4 h2 = hb4[(4 * w + 2) * 64 + l];
    ushort4 h3 = hb4[(4 * w + 3) * 64 + l];
    floatx4 v0 = {bf2f(h0.x), bf2f(h0.y), bf2f(h0.z), bf2f(h0.w)};
    floatx4 v1 = {bf2f(h1.x), bf2f(h1.y), bf2f(h1.z), bf2f(h1.w)};
    floatx4 v2 = {bf2f(h2.x), bf2f(h2.y), bf2f(h2.z), bf2f(h2.w)};
    floatx4 v3 = {bf2f(h3.x), bf2f(h3.y), bf2f(h3.z), bf2f(h3.w)};
    if (tid < CH_) {
        float vv = dvs[(size_t)bh * N_ + c * CH_ + tid];
        w1s[tid] = expf(vv);
        w2s[tid] = expf(0.2f * vv);
    }
    __syncthreads();
    float a0 = w1s[4*w], a1 = w1s[4*w+1], a2 = w1s[4*w+2], a3 = w1s[4*w+3];
    float c0 = w2s[4*w], c1 = w2s[4*w+1], c2 = w2s[4*w+2], c3 = w2s[4*w+3];
    floatx4 q1_1 = a0 * v0;
    floatx4 q1_2 = q1_1 + a1 * v1;
    floatx4 q1_3 = q1_2 + a2 * v2;
    floatx4 tw1  = q1_3 + a3 * v3;
    floatx4 q2_1 = c0 * v0;
    floatx4 q2_2 = q2_1 + c1 * v1;
    floatx4 q2_3 = q2_2 + c2 * v2;
    floatx4 tw2  = q2_3 + c3 * v3;
    T1s[w][l] = tw1; T2s[w][l] = tw2;
    if (tid == 0) {
        float z1 = 0.f, z2 = 0.f;
        #pragma unroll
        for (int r = 0; r < CH_; ++r) { zx1[r] = z1; zx2[r] = z2; z1 += w1s[r]; z2 += w2s[r]; }
        zx1[CH_] = z1; zx2[CH_] = z2;
    }
    __syncthreads();
    floatx4 base1 = {0.f, 0.f, 0.f, 0.f}, base2 = {0.f, 0.f, 0.f, 0.f};
    if (w > 0) { base1 += T1s[0][l]; base2 += T2s[0][l]; }
    if (w > 1) { base1 += T1s[1][l]; base2 += T2s[1][l]; }
    if (w > 2) { base1 += T1s[2][l]; base2 += T2s[2][l]; }
    P1s[4*w+0][l] = base1;         P2s[4*w+0][l] = base2;
    P1s[4*w+1][l] = base1 + q1_1;  P2s[4*w+1][l] = base2 + q2_1;
    P1s[4*w+2][l] = base1 + q1_2;  P2s[4*w+2][l] = base2 + q2_2;
    P1s[4*w+3][l] = base1 + q1_3;  P2s[4*w+3][l] = base2 + q2_3;
    if (w == 3) { P1s[CH_][l] = base1 + tw1; P2s[CH_][l] = base2 + tw2; }
    __syncthreads();

    floatx4 t1 = P1s[CH_][l];
    float tz1 = zx1[CH_];

    for (int t0 = j0; t0 < e0; t0 += 256) {
        if (t0 == j0) {
            sps[tid] = sp0; srs[tid] = sr0; s8s[tid] = s80;   // registers, no latency
        } else {
            int jj = t0 + tid;
            if (jj < e0) { sps[tid] = spos_b[jj]; srs[tid] = srows_b[jj]; s8s[tid] = se8_b[jj]; }
        }
        __syncthreads();
        int cnt = min(256, e0 - t0);
        for (int k = w; k < cnt; k += 4) {           // 4 rows in flight (one per wave)
            int   rr  = sps[k] - c * CH_;            // 0..CH_, uniform per wave
            int   row = srs[k];
            float e8  = s8s[k];
            floatx4 s1 = b1u + (t1 - P1s[rr][l]);
            floatx4 s2 = b2u + P2s[rr][l];
            float den = e8 * (bz1c + (tz1 - zx1[rr])) + (bz2c + zx2[rr]);
            float rden = 1.0f / den;
            floatx4 o = (e8 * s1 + s2) * rden;
            __builtin_nontemporal_store(o,
                (floatx4*)(out + ((size_t)(b * N_ + row)) * (H_ * U_) + hh * U_ + 4 * l));
        }
        __syncthreads();
    }
}

// ---------------- host launch ----------------------------------------------------
extern "C" void kernel_launch(void* const* d_in, const int* in_sizes, int n_in,
                              void* d_out, int out_size, void* d_ws, size_t ws_size,
                              hipStream_t stream) {
    const float* x    = (const float*)d_in[0];
    const float* W    = (const float*)d_in[1];
    const float* asr  = (const float*)d_in[2];
    const float* ads  = (const float*)d_in[3];
    float* out = (float*)d_out;

    char* ws = (char*)d_ws;
    size_t off = 0;
    auto alloc = [&](size_t nfloats) -> float* {
        float* p = (float*)(ws + off);
        off += ((nfloats * 4 + 255) / 256) * 256;
        return p;
    };
    unsigned short* hbuf = (unsigned short*)alloc((size_t)BH_ * N_ * U_ / 2);  // 16.7 MB bf16
    float* srcv  = alloc((size_t)BH_ * N_);
    float* dstv  = alloc((size_t)BH_ * N_);
    float* c_src = alloc(H_ * F_);
    float* c_dst = alloc(H_ * F_);
    float* dvs   = alloc((size_t)BH_ * N_);
    int*   invp  = (int*)alloc((size_t)BH_ * N_);
    int*   srows = (int*)alloc((size_t)BH_ * N_);
    int*   spos  = (int*)alloc((size_t)BH_ * N_);
    float* se8   = alloc((size_t)BH_ * N_);
    int*   cstart= (int*)alloc(BH_ * (NCH_ + 1));
    float* cT1   = alloc((size_t)BH_ * NCH_ * U_);        // 2 MB
    float* cT2   = alloc((size_t)BH_ * NCH_ * U_);
    float* cZ1   = alloc(BH_ * NCH_);
    float* cZ2   = alloc(BH_ * NCH_);
    float* b1    = alloc((size_t)BH_ * NCH_ * U_);
    float* b2    = alloc((size_t)BH_ * NCH_ * U_);
    float* bz1   = alloc(BH_ * NCH_);
    float* bz2   = alloc(BH_ * NCH_);
    unsigned short* xh  = (unsigned short*)alloc((size_t)M_ * F_ / 2);   // 4.2 MB
    unsigned short* whT = (unsigned short*)alloc((size_t)H_ * U_ * F_ / 2);
    (void)ws_size; (void)in_sizes; (void)n_in; (void)out_size;

    prep_w<<<80, 256, 0, stream>>>(W, asr, ads, whT, c_src, c_dst);
    k1b_fused<<<(B_ * N_) / 4, 256, 0, stream>>>(x, c_src, c_dst, xh, srcv, dstv);
    k2_all<<<BH_, 1024, 0, stream>>>(dstv, srcv, dvs, invp, spos, srows, se8, cstart);
    k1_mfma<<<dim3(M_ / 128, U_ / 128, H_), 256, 0, stream>>>(xh, whT, invp, hbuf);
    k3a_partial<<<BH_ * NCH_, 256, 0, stream>>>(hbuf, dvs, cT1, cT2, cZ1, cZ2);
    k3b_combine<<<BH_ * 4, 256, 0, stream>>>(cT1, cT2, cZ1, cZ2, b1, b2, bz1, bz2);
    k3cd_emit<<<BH_ * NCH_, 256, 0, stream>>>(hbuf, dvs, b1, b2, bz1, bz2,
                                              spos, srows, se8, cstart, out);
}